// Round 1
// baseline (345.858 us; speedup 1.0000x reference)
//
#include <hip/hip_runtime.h>
#include <hip/hip_bf16.h>

typedef unsigned short ushortT;
typedef __bf16 bf16x8 __attribute__((ext_vector_type(8)));
typedef float f32x4 __attribute__((ext_vector_type(4)));
typedef float f32x4v __attribute__((ext_vector_type(4)));

#define T_SEQ 2048
#define DH 64
#define NH 16
#define DM 1024
#define TD 3072
#define BATCH 2

__device__ inline ushortT f2bf(float f){
    union { float f; unsigned int u; } a; a.f = f;
    unsigned int r = a.u + 0x7fffu + ((a.u >> 16) & 1u);
    return (ushortT)(r >> 16);
}
__device__ inline float bf2f(ushortT u){
    union { float f; unsigned int u; } a; a.u = ((unsigned int)u) << 16;
    return a.f;
}

// ---------------- cast x (fp32 -> bf16) ----------------
__global__ __launch_bounds__(256) void cast_bf16_kernel(const float* __restrict__ in,
                                                        ushortT* __restrict__ out, int n){
    int i = (blockIdx.x * 256 + threadIdx.x) * 4;
    if (i < n){
        float4 v = *(const float4*)&in[i];
        out[i+0] = f2bf(v.x); out[i+1] = f2bf(v.y);
        out[i+2] = f2bf(v.z); out[i+3] = f2bf(v.w);
    }
}

// ---------------- transpose + cast: in (K,N) fp32 -> out (N,K) bf16 ----------------
__global__ __launch_bounds__(256) void transcast_kernel(const float* __restrict__ in,
                                                        ushortT* __restrict__ out, int K, int N){
    __shared__ float tile[64][65];
    int n0 = blockIdx.x * 64, k0 = blockIdx.y * 64;
    int tid = threadIdx.x;
    int c  = tid & 63;
    int r4 = tid >> 6;
#pragma unroll
    for (int i = 0; i < 16; i++){
        int k = r4 + i * 4;
        tile[k][c] = in[(size_t)(k0 + k) * N + n0 + c];
    }
    __syncthreads();
#pragma unroll
    for (int i = 0; i < 16; i++){
        int n = r4 + i * 4;
        out[(size_t)(n0 + n) * K + k0 + c] = f2bf(tile[c][n]);
    }
}

// ---------------- bf16 MFMA GEMM: C(M,N) = A(M,K) @ BT(N,K)^T + bias ----------------
__device__ inline void store_out(ushortT* C, size_t i, float v){ C[i] = f2bf(v); }
__device__ inline void store_out(float*   C, size_t i, float v){ C[i] = v; }

template <typename OUT>
__global__ __launch_bounds__(256) void gemm_bf16_kernel(const ushortT* __restrict__ A,
                                                        const ushortT* __restrict__ BT,
                                                        const float* __restrict__ bias,
                                                        OUT* __restrict__ C,
                                                        int M, int N, int K){
    __shared__ __align__(16) ushortT As[128][32];
    __shared__ __align__(16) ushortT Bs[128][32];
    int tid = threadIdx.x;
    int m0 = blockIdx.x * 128;
    int n0 = blockIdx.y * 128;
    int wid = tid >> 6, lane = tid & 63;
    int l15 = lane & 15, g = lane >> 4;
    int wr = wid >> 1, wc = wid & 1;

    f32x4 acc[4][4];
#pragma unroll
    for (int i = 0; i < 4; i++)
#pragma unroll
        for (int j = 0; j < 4; j++) acc[i][j] = (f32x4){0.f,0.f,0.f,0.f};

    int srow = tid >> 2;
    int scc  = (tid & 3) * 8;

    for (int k0 = 0; k0 < K; k0 += 32){
        *(bf16x8*)&As[srow][scc]      = *(const bf16x8*)&A [(size_t)(m0 + srow)      * K + k0 + scc];
        *(bf16x8*)&As[64 + srow][scc] = *(const bf16x8*)&A [(size_t)(m0 + 64 + srow) * K + k0 + scc];
        *(bf16x8*)&Bs[srow][scc]      = *(const bf16x8*)&BT[(size_t)(n0 + srow)      * K + k0 + scc];
        *(bf16x8*)&Bs[64 + srow][scc] = *(const bf16x8*)&BT[(size_t)(n0 + 64 + srow) * K + k0 + scc];
        __syncthreads();
        bf16x8 af[4], bfr[4];
#pragma unroll
        for (int mi = 0; mi < 4; mi++) af[mi]  = *(const bf16x8*)&As[wr*64 + mi*16 + l15][g*8];
#pragma unroll
        for (int ni = 0; ni < 4; ni++) bfr[ni] = *(const bf16x8*)&Bs[wc*64 + ni*16 + l15][g*8];
#pragma unroll
        for (int mi = 0; mi < 4; mi++)
#pragma unroll
            for (int ni = 0; ni < 4; ni++)
                acc[mi][ni] = __builtin_amdgcn_mfma_f32_16x16x32_bf16(af[mi], bfr[ni], acc[mi][ni], 0, 0, 0);
        __syncthreads();
    }

#pragma unroll
    for (int mi = 0; mi < 4; mi++){
#pragma unroll
        for (int jj = 0; jj < 4; jj++){
            int mm = m0 + wr*64 + mi*16 + 4*g + jj;
#pragma unroll
            for (int ni = 0; ni < 4; ni++){
                int nn = n0 + wc*64 + ni*16 + l15;
                float v = acc[mi][ni][jj] + bias[nn];
                store_out(C, (size_t)mm * N + nn, v);
            }
        }
    }
}

// ---------------- gate: g=sigmoid(q @ Wg[h]); VgT[b,h,e,t] = g*v  ----------------
__global__ __launch_bounds__(256) void gate_kernel(const ushortT* __restrict__ qkv,
                                                   const float* __restrict__ Wg,
                                                   ushortT* __restrict__ vgT){
    __shared__ float WgL[64][64];
    __shared__ ushortT VT[64][66];
    int tblk = blockIdx.x, bh = blockIdx.y;
    int b = bh >> 4, h = bh & 15;
    int tid = threadIdx.x, wid = tid >> 6, lane = tid & 63;

    for (int i = tid; i < 64*64; i += 256) WgL[i >> 6][i & 63] = Wg[h*4096 + i];
    __syncthreads();

    int t0 = tblk * 64;
#pragma unroll 4
    for (int i = 0; i < 16; i++){
        int tl = wid * 16 + i;
        int t = t0 + tl;
        const ushortT* qrow = qkv + ((size_t)b * T_SEQ + t) * TD + h * DH;
        const ushortT* vrow = qkv + ((size_t)b * T_SEQ + t) * TD + 2*DM + h * DH;
        float s = 0.f;
#pragma unroll
        for (int d = 0; d < 64; d++) s += bf2f(qrow[d]) * WgL[d][lane];
        float gv = 1.f / (1.f + __expf(-s));
        VT[tl][lane] = f2bf(gv * bf2f(vrow[lane]));
    }
    __syncthreads();
    for (int i = tid; i < 64*64; i += 256){
        int e = i >> 6, tl = i & 63;
        vgT[((size_t)bh * DH + e) * T_SEQ + t0 + tl] = VT[tl][e];
    }
}

// ---------------- causal flash attention with gated V ----------------
__global__ __launch_bounds__(256) void attn_kernel(const ushortT* __restrict__ qkv,
                                                   const ushortT* __restrict__ vgT,
                                                   ushortT* __restrict__ obf){
    __shared__ __align__(16) ushortT Plds[4][16][72];
    int qblk = blockIdx.x, bh = blockIdx.y;
    int b = bh >> 4, h = bh & 15;
    int tid = threadIdx.x, wid = tid >> 6, lane = tid & 63;
    int l15 = lane & 15, g = lane >> 4;

    int q0 = qblk * 64;
    int qrowA = q0 + wid * 16 + l15;

    const ushortT* qbase = qkv + ((size_t)b * T_SEQ + qrowA) * TD + h * DH;
    bf16x8 qf0 = *(const bf16x8*)(qbase + 8*g);
    bf16x8 qf1 = *(const bf16x8*)(qbase + 32 + 8*g);

    float m[4], lsum[4];
    f32x4 acc[4];
#pragma unroll
    for (int jj = 0; jj < 4; jj++){ m[jj] = -INFINITY; lsum[jj] = 0.f; }
#pragma unroll
    for (int nt = 0; nt < 4; nt++) acc[nt] = (f32x4){0.f,0.f,0.f,0.f};

    const float scale = 0.125f;
    int kvmax = q0 + 63;

    for (int kv0 = 0; kv0 <= kvmax; kv0 += 64){
        f32x4 s[4];
#pragma unroll
        for (int ns = 0; ns < 4; ns++){
            const ushortT* kbase = qkv + ((size_t)b * T_SEQ + kv0 + ns*16 + l15) * TD + DM + h * DH;
            bf16x8 kf0 = *(const bf16x8*)(kbase + 8*g);
            bf16x8 kf1 = *(const bf16x8*)(kbase + 32 + 8*g);
            f32x4 z = (f32x4){0.f,0.f,0.f,0.f};
            z = __builtin_amdgcn_mfma_f32_16x16x32_bf16(qf0, kf0, z, 0, 0, 0);
            z = __builtin_amdgcn_mfma_f32_16x16x32_bf16(qf1, kf1, z, 0, 0, 0);
            s[ns] = z;
        }
        float alpha[4];
#pragma unroll
        for (int jj = 0; jj < 4; jj++){
            int qr = q0 + wid*16 + 4*g + jj;
            float tmax = -INFINITY;
#pragma unroll
            for (int ns = 0; ns < 4; ns++){
                int key = kv0 + ns*16 + l15;
                float v = s[ns][jj] * scale;
                if (key > qr) v = -INFINITY;
                s[ns][jj] = v;
                tmax = fmaxf(tmax, v);
            }
            tmax = fmaxf(tmax, __shfl_xor(tmax, 1, 64));
            tmax = fmaxf(tmax, __shfl_xor(tmax, 2, 64));
            tmax = fmaxf(tmax, __shfl_xor(tmax, 4, 64));
            tmax = fmaxf(tmax, __shfl_xor(tmax, 8, 64));
            float mnew = fmaxf(m[jj], tmax);
            alpha[jj] = __expf(m[jj] - mnew);
            float rs = 0.f;
#pragma unroll
            for (int ns = 0; ns < 4; ns++){
                float p = __expf(s[ns][jj] - mnew);
                s[ns][jj] = p;
                rs += p;
            }
            rs += __shfl_xor(rs, 1, 64); rs += __shfl_xor(rs, 2, 64);
            rs += __shfl_xor(rs, 4, 64); rs += __shfl_xor(rs, 8, 64);
            lsum[jj] = lsum[jj] * alpha[jj] + rs;
            m[jj] = mnew;
        }
#pragma unroll
        for (int nt = 0; nt < 4; nt++)
#pragma unroll
            for (int jj = 0; jj < 4; jj++) acc[nt][jj] *= alpha[jj];
        // P -> LDS (bf16)
#pragma unroll
        for (int ns = 0; ns < 4; ns++)
#pragma unroll
            for (int jj = 0; jj < 4; jj++)
                Plds[wid][4*g + jj][ns*16 + l15] = f2bf(s[ns][jj]);
        // PV
#pragma unroll
        for (int ks = 0; ks < 2; ks++){
            bf16x8 pa = *(const bf16x8*)&Plds[wid][l15][ks*32 + 8*g];
#pragma unroll
            for (int nt = 0; nt < 4; nt++){
                const ushortT* vb = vgT + ((size_t)bh * DH + nt*16 + l15) * T_SEQ + kv0 + ks*32 + 8*g;
                bf16x8 vf = *(const bf16x8*)vb;
                acc[nt] = __builtin_amdgcn_mfma_f32_16x16x32_bf16(pa, vf, acc[nt], 0, 0, 0);
            }
        }
    }

#pragma unroll
    for (int jj = 0; jj < 4; jj++){
        int t = q0 + wid*16 + 4*g + jj;
        float inv = 1.f / lsum[jj];
#pragma unroll
        for (int nt = 0; nt < 4; nt++){
            obf[((size_t)b * T_SEQ + t) * DM + h*DH + nt*16 + l15] = f2bf(acc[nt][jj] * inv);
        }
    }
}

extern "C" void kernel_launch(void* const* d_in, const int* in_sizes, int n_in,
                              void* d_out, int out_size, void* d_ws, size_t ws_size,
                              hipStream_t stream){
    const float* x    = (const float*)d_in[0];
    const float* Wqkv = (const float*)d_in[1];
    const float* bqkv = (const float*)d_in[2];
    const float* Wg   = (const float*)d_in[3];
    const float* Wout = (const float*)d_in[4];
    const float* bout = (const float*)d_in[5];

    char* ws = (char*)d_ws;
    ushortT* xbf   = (ushortT*)(ws);                 //  8 MB : (4096,1024) bf16
    ushortT* wqkvT = (ushortT*)(ws + 8388608);       //  6 MB : (3072,1024) bf16
    ushortT* woutT = (ushortT*)(ws + 14680064);      //  2 MB : (1024,1024) bf16
    ushortT* qkvb  = (ushortT*)(ws + 16777216);      // 24 MB : (4096,3072) bf16
    ushortT* vgT   = (ushortT*)(ws + 41943040);      //  8 MB : (32,64,2048) bf16
    ushortT* obf   = (ushortT*)(ws + 50331648);      //  8 MB : (4096,1024) bf16

    cast_bf16_kernel<<<4096, 256, 0, stream>>>(x, xbf, 4194304);
    transcast_kernel<<<dim3(48,16), 256, 0, stream>>>(Wqkv, wqkvT, 1024, 3072);
    transcast_kernel<<<dim3(16,16), 256, 0, stream>>>(Wout, woutT, 1024, 1024);
    gemm_bf16_kernel<ushortT><<<dim3(32,24), 256, 0, stream>>>(xbf, wqkvT, bqkv, qkvb, 4096, 3072, 1024);
    gate_kernel<<<dim3(32,32), 256, 0, stream>>>(qkvb, Wg, vgT);
    attn_kernel<<<dim3(32,32), 256, 0, stream>>>(qkvb, vgT, obf);
    gemm_bf16_kernel<float><<<dim3(32,8), 256, 0, stream>>>(obf, woutT, bout, (float*)d_out, 4096, 1024, 1024);
}

// Round 2
// 215.928 us; speedup vs baseline: 1.6017x; 1.6017x over previous
//
#include <hip/hip_runtime.h>
#include <hip/hip_bf16.h>

typedef unsigned short ushortT;
typedef __bf16 bf16x8 __attribute__((ext_vector_type(8)));
typedef float f32x4 __attribute__((ext_vector_type(4)));

#define T_SEQ 2048
#define DH 64
#define NH 16
#define DM 1024
#define TD 3072
#define BATCH 2

__device__ inline ushortT f2bf(float f){
    union { float f; unsigned int u; } a; a.f = f;
    unsigned int r = a.u + 0x7fffu + ((a.u >> 16) & 1u);
    return (ushortT)(r >> 16);
}
__device__ inline float bf2f(ushortT u){
    union { float f; unsigned int u; } a; a.u = ((unsigned int)u) << 16;
    return a.f;
}

__device__ inline void gload_lds16(const void* g, void* l){
    __builtin_amdgcn_global_load_lds((const __attribute__((address_space(1))) void*)g,
                                     (__attribute__((address_space(3))) void*)l, 16, 0, 0);
}

// ---------------- cast x (fp32 -> bf16) ----------------
__global__ __launch_bounds__(256) void cast_bf16_kernel(const float* __restrict__ in,
                                                        ushortT* __restrict__ out, int n){
    int i = (blockIdx.x * 256 + threadIdx.x) * 4;
    if (i < n){
        float4 v = *(const float4*)&in[i];
        out[i+0] = f2bf(v.x); out[i+1] = f2bf(v.y);
        out[i+2] = f2bf(v.z); out[i+3] = f2bf(v.w);
    }
}

// ---------------- transpose + cast: in (K,N) fp32 -> out (N,K) bf16 ----------------
__global__ __launch_bounds__(256) void transcast_kernel(const float* __restrict__ in,
                                                        ushortT* __restrict__ out, int K, int N){
    __shared__ float tile[64][65];
    int n0 = blockIdx.x * 64, k0 = blockIdx.y * 64;
    int tid = threadIdx.x;
    int c  = tid & 63;
    int r4 = tid >> 6;
#pragma unroll
    for (int i = 0; i < 16; i++){
        int k = r4 + i * 4;
        tile[k][c] = in[(size_t)(k0 + k) * N + n0 + c];
    }
    __syncthreads();
#pragma unroll
    for (int i = 0; i < 16; i++){
        int n = r4 + i * 4;
        out[(size_t)(n0 + n) * K + k0 + c] = f2bf(tile[c][n]);
    }
}

// ---------------- bf16 MFMA GEMM: C(M,N) = A(M,K) @ BT(N,K)^T + bias ----------------
__device__ inline void store_out(ushortT* C, size_t i, float v){ C[i] = f2bf(v); }
__device__ inline void store_out(float*   C, size_t i, float v){ C[i] = v; }

template <typename OUT>
__global__ __launch_bounds__(256) void gemm_bf16_kernel(const ushortT* __restrict__ A,
                                                        const ushortT* __restrict__ BT,
                                                        const float* __restrict__ bias,
                                                        OUT* __restrict__ C,
                                                        int M, int N, int K){
    __shared__ __align__(16) ushortT As[128*32];
    __shared__ __align__(16) ushortT Bs[128*32];
    int tid = threadIdx.x;
    int m0 = blockIdx.x * 128;
    int n0 = blockIdx.y * 128;
    int wid = tid >> 6, lane = tid & 63;
    int l15 = lane & 15, g = lane >> 4;
    int wr = wid >> 1, wc = wid & 1;

    f32x4 acc[4][4];
#pragma unroll
    for (int i = 0; i < 4; i++)
#pragma unroll
        for (int j = 0; j < 4; j++) acc[i][j] = (f32x4){0.f,0.f,0.f,0.f};

    int srow = wid * 32 + (lane >> 2);           // rows covered per issue pair
    int sch  = lane & 3;                          // 16B chunk within 64B row

    for (int k0 = 0; k0 < K; k0 += 32){
#pragma unroll
        for (int i = 0; i < 2; i++){
            int row = srow + i * 16;
            const ushortT* asrc = A  + (size_t)(m0 + row) * K + k0 + sch * 8;
            const ushortT* bsrc = BT + (size_t)(n0 + row) * K + k0 + sch * 8;
            gload_lds16(asrc, (char*)As + (wid*2 + i) * 1024);
            gload_lds16(bsrc, (char*)Bs + (wid*2 + i) * 1024);
        }
        __syncthreads();
        bf16x8 af[4], bfr[4];
#pragma unroll
        for (int mi = 0; mi < 4; mi++){
            int r = wr*64 + mi*16 + l15;
            af[mi]  = *(const bf16x8*)(As + r*32 + g*8);
        }
#pragma unroll
        for (int ni = 0; ni < 4; ni++){
            int r = wc*64 + ni*16 + l15;
            bfr[ni] = *(const bf16x8*)(Bs + r*32 + g*8);
        }
#pragma unroll
        for (int mi = 0; mi < 4; mi++)
#pragma unroll
            for (int ni = 0; ni < 4; ni++)
                acc[mi][ni] = __builtin_amdgcn_mfma_f32_16x16x32_bf16(af[mi], bfr[ni], acc[mi][ni], 0, 0, 0);
        __syncthreads();
    }

#pragma unroll
    for (int mi = 0; mi < 4; mi++){
#pragma unroll
        for (int jj = 0; jj < 4; jj++){
            int mm = m0 + wr*64 + mi*16 + 4*g + jj;
#pragma unroll
            for (int ni = 0; ni < 4; ni++){
                int nn = n0 + wc*64 + ni*16 + l15;
                float v = acc[mi][ni][jj] + bias[nn];
                store_out(C, (size_t)mm * N + nn, v);
            }
        }
    }
}

// ---------------- gate: g=sigmoid(q @ Wg[h]); VgT[b,h,e,t] = g*v  ----------------
__global__ __launch_bounds__(256) void gate_kernel(const ushortT* __restrict__ qkv,
                                                   const float* __restrict__ Wg,
                                                   ushortT* __restrict__ vgT){
    __shared__ float WgL[64][64];
    __shared__ ushortT VT[64][66];
    int tblk = blockIdx.x, bh = blockIdx.y;
    int b = bh >> 4, h = bh & 15;
    int tid = threadIdx.x, wid = tid >> 6, lane = tid & 63;

    for (int i = tid; i < 64*64; i += 256) WgL[i >> 6][i & 63] = Wg[h*4096 + i];
    __syncthreads();

    int t0 = tblk * 64;
#pragma unroll 4
    for (int i = 0; i < 16; i++){
        int tl = wid * 16 + i;
        int t = t0 + tl;
        const ushortT* qrow = qkv + ((size_t)b * T_SEQ + t) * TD + h * DH;
        const ushortT* vrow = qkv + ((size_t)b * T_SEQ + t) * TD + 2*DM + h * DH;
        float s = 0.f;
#pragma unroll
        for (int d = 0; d < 64; d++) s += bf2f(qrow[d]) * WgL[d][lane];
        float gv = 1.f / (1.f + __expf(-s));
        VT[tl][lane] = f2bf(gv * bf2f(vrow[lane]));
    }
    __syncthreads();
    for (int i = tid; i < 64*64; i += 256){
        int e = i >> 6, tl = i & 63;
        vgT[((size_t)bh * DH + e) * T_SEQ + t0 + tl] = VT[tl][e];
    }
}

// ---------------- causal flash attention with gated V ----------------
// grid: (bh=32 fast, qblk=32)  -- balanced causal work per CU
__global__ __launch_bounds__(256) void attn_kernel(const ushortT* __restrict__ qkv,
                                                   const ushortT* __restrict__ vgT,
                                                   ushortT* __restrict__ obf){
    __shared__ __align__(16) ushortT Ks[2][64*64];
    __shared__ __align__(16) ushortT Vs[2][64*64];
    __shared__ __align__(16) ushortT Plds[4][16][72];
    int bh = blockIdx.x, qblk = blockIdx.y;
    int b = bh >> 4, h = bh & 15;
    int tid = threadIdx.x, wid = tid >> 6, lane = tid & 63;
    int l15 = lane & 15, g = lane >> 4;
    int q0 = qblk * 64;

    const ushortT* Kg = qkv + (size_t)b * T_SEQ * TD + DM + h * DH;  // + (kv0+row)*TD
    const ushortT* Vg = vgT + (size_t)bh * DH * T_SEQ;               // + row*T_SEQ + kv0

    // staging lane mapping: per wave-issue 16B/lane, rows of 128B (8 chunks)
    int st_row = wid*16 + (lane >> 3);      // + i*8
    int st_c   = lane & 7;

#define STAGE_TILE(bufidx, kv0)                                                          \
    {                                                                                    \
        _Pragma("unroll")                                                                \
        for (int i_ = 0; i_ < 2; i_++){                                                  \
            int row_ = st_row + i_*8;                                                    \
            int sc_  = st_c ^ (row_ & 7);                                                \
            const ushortT* ksrc_ = Kg + (size_t)((kv0) + row_) * TD + sc_*8;             \
            const ushortT* vsrc_ = Vg + (size_t)row_ * T_SEQ + (kv0) + sc_*8;            \
            gload_lds16(ksrc_, (char*)Ks[bufidx] + (wid*2 + i_)*1024);                   \
            gload_lds16(vsrc_, (char*)Vs[bufidx] + (wid*2 + i_)*1024);                   \
        }                                                                                \
    }

    // Q fragments, scale folded in (exact: *2^-3)
    int qrow = q0 + wid*16 + l15;
    const ushortT* qbase = qkv + ((size_t)b * T_SEQ + qrow) * TD + h * DH;
    bf16x8 qf0 = *(const bf16x8*)(qbase + 8*g);
    bf16x8 qf1 = *(const bf16x8*)(qbase + 32 + 8*g);
#pragma unroll
    for (int j = 0; j < 8; j++){
        qf0[j] = (__bf16)((float)qf0[j] * 0.125f);
        qf1[j] = (__bf16)((float)qf1[j] * 0.125f);
    }

    float m[4], lsum[4];
    f32x4 acc[4];
#pragma unroll
    for (int jj = 0; jj < 4; jj++){ m[jj] = -INFINITY; lsum[jj] = 0.f; }
#pragma unroll
    for (int nt = 0; nt < 4; nt++) acc[nt] = (f32x4){0.f,0.f,0.f,0.f};

    int ntiles = qblk + 1;
    STAGE_TILE(0, 0);
    __syncthreads();

    for (int t = 0; t < ntiles; t++){
        int buf = t & 1;
        if (t + 1 < ntiles) STAGE_TILE(buf ^ 1, (t+1)*64);

        const ushortT* Kb = Ks[buf];
        const ushortT* Vb = Vs[buf];

        // QK^T
        f32x4 s[4];
#pragma unroll
        for (int ns = 0; ns < 4; ns++){
            int kr = ns*16 + l15;
            bf16x8 kf0 = *(const bf16x8*)(Kb + kr*64 + ((g     ) ^ (kr & 7))*8);
            bf16x8 kf1 = *(const bf16x8*)(Kb + kr*64 + ((4 + g) ^ (kr & 7))*8);
            f32x4 z = (f32x4){0.f,0.f,0.f,0.f};
            z = __builtin_amdgcn_mfma_f32_16x16x32_bf16(qf0, kf0, z, 0, 0, 0);
            z = __builtin_amdgcn_mfma_f32_16x16x32_bf16(qf1, kf1, z, 0, 0, 0);
            s[ns] = z;
        }

        bool diag = (t == qblk);
        float alpha[4];
#pragma unroll
        for (int jj = 0; jj < 4; jj++){
            float tmax = -INFINITY;
            if (diag){
                int qr = wid*16 + 4*g + jj;      // row within tile; keys rel ns*16+l15
#pragma unroll
                for (int ns = 0; ns < 4; ns++){
                    if (ns*16 + l15 > qr) s[ns][jj] = -INFINITY;
                    tmax = fmaxf(tmax, s[ns][jj]);
                }
            } else {
#pragma unroll
                for (int ns = 0; ns < 4; ns++) tmax = fmaxf(tmax, s[ns][jj]);
            }
            tmax = fmaxf(tmax, __shfl_xor(tmax, 1, 64));
            tmax = fmaxf(tmax, __shfl_xor(tmax, 2, 64));
            tmax = fmaxf(tmax, __shfl_xor(tmax, 4, 64));
            tmax = fmaxf(tmax, __shfl_xor(tmax, 8, 64));
            float mnew = fmaxf(m[jj], tmax);
            alpha[jj] = __expf(m[jj] - mnew);
            float rs = 0.f;
#pragma unroll
            for (int ns = 0; ns < 4; ns++){
                float p = __expf(s[ns][jj] - mnew);
                s[ns][jj] = p;
                rs += p;
            }
            rs += __shfl_xor(rs, 1, 64); rs += __shfl_xor(rs, 2, 64);
            rs += __shfl_xor(rs, 4, 64); rs += __shfl_xor(rs, 8, 64);
            lsum[jj] = lsum[jj] * alpha[jj] + rs;
            m[jj] = mnew;
        }
#pragma unroll
        for (int nt = 0; nt < 4; nt++)
#pragma unroll
            for (int jj = 0; jj < 4; jj++) acc[nt][jj] *= alpha[jj];

        // P -> per-wave LDS tile (bf16), then PV
#pragma unroll
        for (int ns = 0; ns < 4; ns++)
#pragma unroll
            for (int jj = 0; jj < 4; jj++)
                Plds[wid][4*g + jj][ns*16 + l15] = f2bf(s[ns][jj]);

#pragma unroll
        for (int ks = 0; ks < 2; ks++){
            bf16x8 pa = *(const bf16x8*)&Plds[wid][l15][ks*32 + 8*g];
#pragma unroll
            for (int nt = 0; nt < 4; nt++){
                int e = nt*16 + l15;
                bf16x8 vf = *(const bf16x8*)(Vb + e*64 + ((ks*4 + g) ^ (e & 7))*8);
                acc[nt] = __builtin_amdgcn_mfma_f32_16x16x32_bf16(pa, vf, acc[nt], 0, 0, 0);
            }
        }
        __syncthreads();
    }
#undef STAGE_TILE

#pragma unroll
    for (int jj = 0; jj < 4; jj++){
        int t = q0 + wid*16 + 4*g + jj;
        float inv = 1.f / lsum[jj];
#pragma unroll
        for (int nt = 0; nt < 4; nt++){
            obf[((size_t)b * T_SEQ + t) * DM + h*DH + nt*16 + l15] = f2bf(acc[nt][jj] * inv);
        }
    }
}

extern "C" void kernel_launch(void* const* d_in, const int* in_sizes, int n_in,
                              void* d_out, int out_size, void* d_ws, size_t ws_size,
                              hipStream_t stream){
    const float* x    = (const float*)d_in[0];
    const float* Wqkv = (const float*)d_in[1];
    const float* bqkv = (const float*)d_in[2];
    const float* Wg   = (const float*)d_in[3];
    const float* Wout = (const float*)d_in[4];
    const float* bout = (const float*)d_in[5];

    char* ws = (char*)d_ws;
    ushortT* xbf   = (ushortT*)(ws);                 //  8 MB : (4096,1024) bf16
    ushortT* wqkvT = (ushortT*)(ws + 8388608);       //  6 MB : (3072,1024) bf16
    ushortT* woutT = (ushortT*)(ws + 14680064);      //  2 MB : (1024,1024) bf16
    ushortT* qkvb  = (ushortT*)(ws + 16777216);      // 24 MB : (4096,3072) bf16
    ushortT* vgT   = (ushortT*)(ws + 41943040);      //  8 MB : (32,64,2048) bf16
    ushortT* obf   = (ushortT*)(ws + 50331648);      //  8 MB : (4096,1024) bf16

    cast_bf16_kernel<<<4096, 256, 0, stream>>>(x, xbf, 4194304);
    transcast_kernel<<<dim3(48,16), 256, 0, stream>>>(Wqkv, wqkvT, 1024, 3072);
    transcast_kernel<<<dim3(16,16), 256, 0, stream>>>(Wout, woutT, 1024, 1024);
    gemm_bf16_kernel<ushortT><<<dim3(32,24), 256, 0, stream>>>(xbf, wqkvT, bqkv, qkvb, 4096, 3072, 1024);
    gate_kernel<<<dim3(32,32), 256, 0, stream>>>(qkvb, Wg, vgT);
    attn_kernel<<<dim3(32,32), 256, 0, stream>>>(qkvb, vgT, obf);
    gemm_bf16_kernel<float><<<dim3(32,8), 256, 0, stream>>>(obf, woutT, bout, (float*)d_out, 4096, 1024, 1024);
}

// Round 3
// 185.421 us; speedup vs baseline: 1.8653x; 1.1645x over previous
//
#include <hip/hip_runtime.h>
#include <hip/hip_bf16.h>

typedef unsigned short ushortT;
typedef __bf16 bf16x8 __attribute__((ext_vector_type(8)));
typedef float f32x4 __attribute__((ext_vector_type(4)));

#define T_SEQ 2048
#define DH 64
#define NH 16
#define DM 1024
#define TD 3072
#define BATCH 2

__device__ inline ushortT f2bf(float f){
    union { float f; unsigned int u; } a; a.f = f;
    unsigned int r = a.u + 0x7fffu + ((a.u >> 16) & 1u);
    return (ushortT)(r >> 16);
}
__device__ inline float bf2f(ushortT u){
    union { float f; unsigned int u; } a; a.u = ((unsigned int)u) << 16;
    return a.f;
}

__device__ inline void gload_lds16(const void* g, void* l){
    __builtin_amdgcn_global_load_lds((const __attribute__((address_space(1))) void*)g,
                                     (__attribute__((address_space(3))) void*)l, 16, 0, 0);
}

// ---------------- cast x (fp32 -> bf16) ----------------
__global__ __launch_bounds__(256) void cast_bf16_kernel(const float* __restrict__ in,
                                                        ushortT* __restrict__ out, int n){
    int i = (blockIdx.x * 256 + threadIdx.x) * 4;
    if (i < n){
        float4 v = *(const float4*)&in[i];
        out[i+0] = f2bf(v.x); out[i+1] = f2bf(v.y);
        out[i+2] = f2bf(v.z); out[i+3] = f2bf(v.w);
    }
}

// ---------------- transpose + cast: in (K,N) fp32 -> out (N,K) bf16 ----------------
__global__ __launch_bounds__(256) void transcast_kernel(const float* __restrict__ in,
                                                        ushortT* __restrict__ out, int K, int N){
    __shared__ float tile[64][65];
    int n0 = blockIdx.x * 64, k0 = blockIdx.y * 64;
    int tid = threadIdx.x;
    int c  = tid & 63;
    int r4 = tid >> 6;
#pragma unroll
    for (int i = 0; i < 16; i++){
        int k = r4 + i * 4;
        tile[k][c] = in[(size_t)(k0 + k) * N + n0 + c];
    }
    __syncthreads();
#pragma unroll
    for (int i = 0; i < 16; i++){
        int n = r4 + i * 4;
        out[(size_t)(n0 + n) * K + k0 + c] = f2bf(tile[c][n]);
    }
}

// ---------------- bf16 MFMA GEMM: C(M,N) = A(M,K) @ BT(N,K)^T + bias ----------------
__device__ inline void store_out(ushortT* C, size_t i, float v){ C[i] = f2bf(v); }
__device__ inline void store_out(float*   C, size_t i, float v){ C[i] = v; }

template <typename OUT>
__global__ __launch_bounds__(256) void gemm_bf16_kernel(const ushortT* __restrict__ A,
                                                        const ushortT* __restrict__ BT,
                                                        const float* __restrict__ bias,
                                                        OUT* __restrict__ C,
                                                        int M, int N, int K){
    __shared__ __align__(16) ushortT As[128*32];
    __shared__ __align__(16) ushortT Bs[128*32];
    int tid = threadIdx.x;
    int m0 = blockIdx.x * 128;
    int n0 = blockIdx.y * 128;
    int wid = tid >> 6, lane = tid & 63;
    int l15 = lane & 15, g = lane >> 4;
    int wr = wid >> 1, wc = wid & 1;

    f32x4 acc[4][4];
#pragma unroll
    for (int i = 0; i < 4; i++)
#pragma unroll
        for (int j = 0; j < 4; j++) acc[i][j] = (f32x4){0.f,0.f,0.f,0.f};

    int srow = wid * 32 + (lane >> 2);
    int sch  = lane & 3;

    for (int k0 = 0; k0 < K; k0 += 32){
#pragma unroll
        for (int i = 0; i < 2; i++){
            int row = srow + i * 16;
            const ushortT* asrc = A  + (size_t)(m0 + row) * K + k0 + sch * 8;
            const ushortT* bsrc = BT + (size_t)(n0 + row) * K + k0 + sch * 8;
            gload_lds16(asrc, (char*)As + (wid*2 + i) * 1024);
            gload_lds16(bsrc, (char*)Bs + (wid*2 + i) * 1024);
        }
        __syncthreads();
        bf16x8 af[4], bfr[4];
#pragma unroll
        for (int mi = 0; mi < 4; mi++){
            int r = wr*64 + mi*16 + l15;
            af[mi]  = *(const bf16x8*)(As + r*32 + g*8);
        }
#pragma unroll
        for (int ni = 0; ni < 4; ni++){
            int r = wc*64 + ni*16 + l15;
            bfr[ni] = *(const bf16x8*)(Bs + r*32 + g*8);
        }
#pragma unroll
        for (int mi = 0; mi < 4; mi++)
#pragma unroll
            for (int ni = 0; ni < 4; ni++)
                acc[mi][ni] = __builtin_amdgcn_mfma_f32_16x16x32_bf16(af[mi], bfr[ni], acc[mi][ni], 0, 0, 0);
        __syncthreads();
    }

#pragma unroll
    for (int mi = 0; mi < 4; mi++){
#pragma unroll
        for (int jj = 0; jj < 4; jj++){
            int mm = m0 + wr*64 + mi*16 + 4*g + jj;
#pragma unroll
            for (int ni = 0; ni < 4; ni++){
                int nn = n0 + wc*64 + ni*16 + l15;
                float v = acc[mi][ni][jj] + bias[nn];
                store_out(C, (size_t)mm * N + nn, v);
            }
        }
    }
}

// ---------------- gate: g=sigmoid(q @ Wg[h]); VgT[b,h,e,t] = g*v  ----------------
__global__ __launch_bounds__(256) void gate_kernel(const ushortT* __restrict__ qkv,
                                                   const float* __restrict__ Wg,
                                                   ushortT* __restrict__ vgT){
    __shared__ float WgL[64][64];
    __shared__ ushortT VT[64][66];
    int tblk = blockIdx.x, bh = blockIdx.y;
    int b = bh >> 4, h = bh & 15;
    int tid = threadIdx.x, wid = tid >> 6, lane = tid & 63;

    for (int i = tid; i < 64*64; i += 256) WgL[i >> 6][i & 63] = Wg[h*4096 + i];
    __syncthreads();

    int t0 = tblk * 64;
#pragma unroll 4
    for (int i = 0; i < 16; i++){
        int tl = wid * 16 + i;
        int t = t0 + tl;
        const ushortT* qrow = qkv + ((size_t)b * T_SEQ + t) * TD + h * DH;
        const ushortT* vrow = qkv + ((size_t)b * T_SEQ + t) * TD + 2*DM + h * DH;
        float s = 0.f;
#pragma unroll
        for (int d = 0; d < 64; d++) s += bf2f(qrow[d]) * WgL[d][lane];
        float gv = 1.f / (1.f + __expf(-s));
        VT[tl][lane] = f2bf(gv * bf2f(vrow[lane]));
    }
    __syncthreads();
    for (int i = tid; i < 64*64; i += 256){
        int e = i >> 6, tl = i & 63;
        vgT[((size_t)bh * DH + e) * T_SEQ + t0 + tl] = VT[tl][e];
    }
}

// ---------------- causal flash attention with gated V ----------------
// grid: (bh=32, pair=16); block handles qblk = pair and qblk = 31-pair
// => exactly 33 kv-tiles per block (balanced causal work).
// Swapped QK^T: s = mfma(K, Q) so q lives on lane axis (l15), keys in regs.
__global__ __launch_bounds__(256) void attn_kernel(const ushortT* __restrict__ qkv,
                                                   const ushortT* __restrict__ vgT,
                                                   ushortT* __restrict__ obf){
    __shared__ __align__(16) ushortT Ks[2][64*64];
    __shared__ __align__(16) ushortT Vs[2][64*64];
    __shared__ __align__(16) ushortT Plds[4][16][72];
    __shared__ __align__(16) float Alds[4][16];
    int bh = blockIdx.x, pairid = blockIdx.y;
    int b = bh >> 4, h = bh & 15;
    int tid = threadIdx.x, wid = tid >> 6, lane = tid & 63;
    int l15 = lane & 15, g = lane >> 4;

    const ushortT* Kg = qkv + (size_t)b * T_SEQ * TD + DM + h * DH;
    const ushortT* Vg = vgT + (size_t)bh * DH * T_SEQ;

    int st_row = wid*16 + (lane >> 3);
    int st_c   = lane & 7;

#define STAGE_TILE(bufidx, kv0)                                                          \
    {                                                                                    \
        _Pragma("unroll")                                                                \
        for (int i_ = 0; i_ < 2; i_++){                                                  \
            int row_ = st_row + i_*8;                                                    \
            int sc_  = st_c ^ (row_ & 7);                                                \
            const ushortT* ksrc_ = Kg + (size_t)((kv0) + row_) * TD + sc_*8;             \
            const ushortT* vsrc_ = Vg + (size_t)row_ * T_SEQ + (kv0) + sc_*8;            \
            gload_lds16(ksrc_, (char*)Ks[bufidx] + (wid*2 + i_)*1024);                   \
            gload_lds16(vsrc_, (char*)Vs[bufidx] + (wid*2 + i_)*1024);                   \
        }                                                                                \
    }

    int qbs[2] = { pairid, 31 - pairid };

    for (int qi = 0; qi < 2; qi++){
        int qblk = qbs[qi];
        int q0 = qblk * 64;

        // Q fragments (B-operand: row = q = l15), scale folded in (exact *2^-3)
        int qrow = q0 + wid*16 + l15;
        const ushortT* qbase = qkv + ((size_t)b * T_SEQ + qrow) * TD + h * DH;
        bf16x8 qf0 = *(const bf16x8*)(qbase + 8*g);
        bf16x8 qf1 = *(const bf16x8*)(qbase + 32 + 8*g);
#pragma unroll
        for (int j = 0; j < 8; j++){
            qf0[j] = (__bf16)((float)qf0[j] * 0.125f);
            qf1[j] = (__bf16)((float)qf1[j] * 0.125f);
        }

        float m_ = -INFINITY, lsum = 0.f;
        f32x4 acc[4];
#pragma unroll
        for (int nt = 0; nt < 4; nt++) acc[nt] = (f32x4){0.f,0.f,0.f,0.f};

        int ntiles = qblk + 1;
        STAGE_TILE(0, 0);
        __syncthreads();

        for (int t = 0; t < ntiles; t++){
            int buf = t & 1;
            if (t + 1 < ntiles) STAGE_TILE(buf ^ 1, (t+1)*64);

            const ushortT* Kb = Ks[buf];
            const ushortT* Vb = Vs[buf];

            // QK^T swapped: s[ns] rows = keys (ns*16 + 4g+jj), col = q (l15)
            f32x4 s[4];
#pragma unroll
            for (int ns = 0; ns < 4; ns++){
                int kr = ns*16 + l15;
                bf16x8 kf0 = *(const bf16x8*)(Kb + kr*64 + ((g     ) ^ (kr & 7))*8);
                bf16x8 kf1 = *(const bf16x8*)(Kb + kr*64 + ((4 + g) ^ (kr & 7))*8);
                f32x4 z = (f32x4){0.f,0.f,0.f,0.f};
                z = __builtin_amdgcn_mfma_f32_16x16x32_bf16(kf0, qf0, z, 0, 0, 0);
                z = __builtin_amdgcn_mfma_f32_16x16x32_bf16(kf1, qf1, z, 0, 0, 0);
                s[ns] = z;
            }

            // in-register online softmax (one q per lane)
            float tmax = -INFINITY;
            if (t == qblk){
                int qrel = wid*16 + l15;
#pragma unroll
                for (int ns = 0; ns < 4; ns++){
                    int kbase = ns*16 + 4*g;
#pragma unroll
                    for (int jj = 0; jj < 4; jj++){
                        if (kbase + jj > qrel) s[ns][jj] = -INFINITY;
                        tmax = fmaxf(tmax, s[ns][jj]);
                    }
                }
            } else {
#pragma unroll
                for (int ns = 0; ns < 4; ns++)
#pragma unroll
                    for (int jj = 0; jj < 4; jj++) tmax = fmaxf(tmax, s[ns][jj]);
            }
            tmax = fmaxf(tmax, __shfl_xor(tmax, 16, 64));
            tmax = fmaxf(tmax, __shfl_xor(tmax, 32, 64));
            float mnew = fmaxf(m_, tmax);
            float alpha = __expf(m_ - mnew);
            float rs = 0.f;
#pragma unroll
            for (int ns = 0; ns < 4; ns++)
#pragma unroll
                for (int jj = 0; jj < 4; jj++){
                    float p = __expf(s[ns][jj] - mnew);
                    s[ns][jj] = p;
                    rs += p;
                }
            rs += __shfl_xor(rs, 16, 64);
            rs += __shfl_xor(rs, 32, 64);
            lsum = lsum * alpha + rs;
            m_ = mnew;

            // P -> LDS: lane owns keys [ns*16+4g .. +3] of query l15 -> b64 writes
#pragma unroll
            for (int ns = 0; ns < 4; ns++){
                union { ushortT u[4]; uint2 v; } pk;
#pragma unroll
                for (int jj = 0; jj < 4; jj++) pk.u[jj] = f2bf(s[ns][jj]);
                *(uint2*)&Plds[wid][l15][ns*16 + 4*g] = pk.v;
            }

            // broadcast alpha from lane-axis q (l15) to row-axis q (4g+jj)
            Alds[wid][l15] = alpha;
            f32x4 a4 = *(const f32x4*)&Alds[wid][4*g];
#pragma unroll
            for (int nt = 0; nt < 4; nt++)
#pragma unroll
                for (int jj = 0; jj < 4; jj++) acc[nt][jj] *= a4[jj];

            // PV: A = P (rows q=l15), B = VgT (rows e=l15); D rows q=4g+jj, col e=l15
#pragma unroll
            for (int ks = 0; ks < 2; ks++){
                bf16x8 pa = *(const bf16x8*)&Plds[wid][l15][ks*32 + 8*g];
#pragma unroll
                for (int nt = 0; nt < 4; nt++){
                    int e = nt*16 + l15;
                    bf16x8 vf = *(const bf16x8*)(Vb + e*64 + ((ks*4 + g) ^ (e & 7))*8);
                    acc[nt] = __builtin_amdgcn_mfma_f32_16x16x32_bf16(pa, vf, acc[nt], 0, 0, 0);
                }
            }
            __syncthreads();
        }

        // epilogue: broadcast 1/lsum to row-axis q, write O
        Alds[wid][l15] = 1.f / lsum;
        f32x4 i4 = *(const f32x4*)&Alds[wid][4*g];
#pragma unroll
        for (int jj = 0; jj < 4; jj++){
            int t = q0 + wid*16 + 4*g + jj;
#pragma unroll
            for (int nt = 0; nt < 4; nt++){
                obf[((size_t)b * T_SEQ + t) * DM + h*DH + nt*16 + l15] = f2bf(acc[nt][jj] * i4[jj]);
            }
        }
    }
#undef STAGE_TILE
}

extern "C" void kernel_launch(void* const* d_in, const int* in_sizes, int n_in,
                              void* d_out, int out_size, void* d_ws, size_t ws_size,
                              hipStream_t stream){
    const float* x    = (const float*)d_in[0];
    const float* Wqkv = (const float*)d_in[1];
    const float* bqkv = (const float*)d_in[2];
    const float* Wg   = (const float*)d_in[3];
    const float* Wout = (const float*)d_in[4];
    const float* bout = (const float*)d_in[5];

    char* ws = (char*)d_ws;
    ushortT* xbf   = (ushortT*)(ws);                 //  8 MB : (4096,1024) bf16
    ushortT* wqkvT = (ushortT*)(ws + 8388608);       //  6 MB : (3072,1024) bf16
    ushortT* woutT = (ushortT*)(ws + 14680064);      //  2 MB : (1024,1024) bf16
    ushortT* qkvb  = (ushortT*)(ws + 16777216);      // 24 MB : (4096,3072) bf16
    ushortT* vgT   = (ushortT*)(ws + 41943040);      //  8 MB : (32,64,2048) bf16
    ushortT* obf   = (ushortT*)(ws + 50331648);      //  8 MB : (4096,1024) bf16

    cast_bf16_kernel<<<4096, 256, 0, stream>>>(x, xbf, 4194304);
    transcast_kernel<<<dim3(48,16), 256, 0, stream>>>(Wqkv, wqkvT, 1024, 3072);
    transcast_kernel<<<dim3(16,16), 256, 0, stream>>>(Wout, woutT, 1024, 1024);
    gemm_bf16_kernel<ushortT><<<dim3(32,24), 256, 0, stream>>>(xbf, wqkvT, bqkv, qkvb, 4096, 3072, 1024);
    gate_kernel<<<dim3(32,32), 256, 0, stream>>>(qkvb, Wg, vgT);
    attn_kernel<<<dim3(32,16), 256, 0, stream>>>(qkvb, vgT, obf);
    gemm_bf16_kernel<float><<<dim3(32,8), 256, 0, stream>>>(obf, woutT, bout, (float*)d_out, 4096, 1024, 1024);
}